// Round 2
// baseline (17864.297 us; speedup 1.0000x reference)
//
#include <hip/hip_runtime.h>
#include <hip/hip_bf16.h>

#define H     768
#define G3    2304
#define BATCH 16
#define TLEN  1024
#define DOUT  512
#define SLICE 32
#define WPG   24      // workgroups per group (768/32)
#define NWG   96      // 4 groups * 24
#define NTHR  384     // 6 waves

typedef __attribute__((ext_vector_type(8))) short short8;
typedef __attribute__((ext_vector_type(4))) float f32x4;

union U8 { short8 s; unsigned u[4]; };

__device__ __forceinline__ float b2f(ushort u) {
  union { unsigned int ui; float f; } v; v.ui = ((unsigned int)u) << 16; return v.f;
}
__device__ __forceinline__ ushort f2b(float f) {
  union { float f; unsigned int ui; } v; v.f = f;
  unsigned int u = v.ui;
  return (ushort)((u + 0x7fffu + ((u >> 16) & 1u)) >> 16);
}

// 16-byte-granular load of 8 consecutive elements as bf16 fragment.
// bf=true: data is bf16. bf=false: data is fp32, truncate-pack via v_perm.
__device__ __forceinline__ short8 loadA8(const void* base, bool bf, size_t eidx) {
  if (bf) return *(const short8*)((const ushort*)base + eidx);
  const uint4* f = (const uint4*)((const float*)base + eidx);
  uint4 lo = f[0];
  uint4 hi = f[1];
  U8 r;
  r.u[0] = __builtin_amdgcn_perm(lo.y, lo.x, 0x07060302);
  r.u[1] = __builtin_amdgcn_perm(lo.w, lo.z, 0x07060302);
  r.u[2] = __builtin_amdgcn_perm(hi.y, hi.x, 0x07060302);
  r.u[3] = __builtin_amdgcn_perm(hi.w, hi.z, 0x07060302);
  return r.s;
}

// RNE variant for once-loaded weights.
__device__ __forceinline__ short8 loadW8(const void* base, bool bf, size_t eidx) {
  if (bf) return *(const short8*)((const ushort*)base + eidx);
  const float* f = (const float*)base + eidx;
  short8 r;
  #pragma unroll
  for (int i = 0; i < 8; i++) r[i] = (short)f2b(f[i]);
  return r;
}

__device__ __forceinline__ float loadS(const void* p, bool bf, size_t i) {
  return bf ? b2f(((const ushort*)p)[i]) : ((const float*)p)[i];
}

// Block-uniform dtype sniff: low 16 bits of dwords of x. bf16-packed ->
// sane bf16 exponent ~99%; fp32 -> uniform mantissa bits ~12%.
__device__ __forceinline__ bool detect_bf16(const unsigned* xw, int tid, int nthr, int* sh) {
  if (tid == 0) *sh = 0;
  __syncthreads();
  int c = 0;
  for (int i = tid; i < 4096; i += nthr) {
    int e = (int)((xw[i] >> 7) & 0xFF);
    c += (e >= 110 && e <= 140) ? 1 : 0;
  }
  atomicAdd(sh, c);
  __syncthreads();
  return *sh > 2048;
}

// ---------------------------------------------------------------------------
// Persistent pipelined GRU scan (unchanged structure; dtype-robust loads).
// Groups: 0=GX1 (w_ih1 @ x[t]), 1=L1 (w_hh1 @ h1 + combine),
//         2=GX2 (w_ih2 @ h1),   3=GH2 (w_hh2 @ h2 + combine, writes y2)
// ---------------------------------------------------------------------------
__global__ __launch_bounds__(NTHR) void scan_kernel(
    const void* __restrict__ x,        // [16][1024][768]
    const void* __restrict__ w_ih,     // [2][2304][768]
    const void* __restrict__ w_hh,     // [2][2304][768]
    const void* __restrict__ b_ih,     // [2][2304]
    const void* __restrict__ b_hh,     // [2][2304]
    unsigned int* cnt,                 // barrier counter (zeroed)
    unsigned int* dflag,               // dtype flag out (for fc)
    ushort* h1buf,                     // [2][16][768] bf16 (zeroed)
    ushort* h2buf,                     // [2][16][768] bf16 (zeroed)
    float*  gx1buf,                    // [2][16][2304] f32
    float*  gx2buf,                    // [2][16][2304] f32
    ushort* y2)                        // [16][1024][768] bf16
{
  const int wg   = blockIdx.x;
  const int grp  = wg / WPG;           // 0..3
  const int wgi  = wg % WPG;           // 0..23 -> gate columns [wgi*32, wgi*32+32)
  const int tid  = threadIdx.x;
  const int wave = tid >> 6;           // 0..5
  const int lane = tid & 63;
  const int col  = lane & 15;
  const int quad = lane >> 4;          // 0..3

  __shared__ float ghs[96 * 17];       // gh slice [gate 0..95][batch], padded
  __shared__ float hold[BATCH * SLICE];// persistent fp32 h slice [b][j]
  __shared__ float bih_s[96], bhh_s[96];
  __shared__ int   detsh;

  const bool isbf = detect_bf16((const unsigned*)x, tid, NTHR, &detsh);
  if (tid == 0) dflag[0] = isbf ? 1u : 0u;

  for (int i = tid; i < BATCH * SLICE; i += NTHR) hold[i] = 0.0f;

  if (grp == 1 || grp == 3) {
    size_t boff = (grp == 3) ? (size_t)G3 : 0;
    for (int gf = tid; gf < 96; gf += NTHR) {
      size_t gidx = boff + (size_t)(gf >> 5) * H + wgi * SLICE + (gf & 31);
      bih_s[gf] = loadS(b_ih, isbf, gidx);
      bhh_s[gf] = loadS(b_hh, isbf, gidx);
    }
  }

  // ---- load this wave's B-fragments (16 gate rows x K=768) into registers --
  const void* Wmat = (grp == 0 || grp == 2) ? w_ih : w_hh;
  const size_t woff = (grp >= 2) ? (size_t)G3 * H : 0;
  const int gate   = wave >> 1;                       // 0=r,1=z,2=n
  const int gfbase = gate * SLICE + (wave & 1) * 16;  // within-wg flat gate base
  const int nrow   = gate * H + wgi * SLICE + (wave & 1) * 16 + col;
  const size_t wbase = woff + (size_t)nrow * H + quad * 8;

  short8 bfrag[24];
  #pragma unroll
  for (int kk = 0; kk < 24; kk++)
    bfrag[kk] = loadW8(Wmat, isbf, wbase + kk * 32);

  __syncthreads();

  unsigned int target = 0;
  for (int t = 0; t < TLEN + 3; t++) {
    const int par = t & 1;
    int tau;
    if      (grp == 0) tau = t;
    else if (grp == 1) tau = t - 1;
    else if (grp == 2) tau = t - 2;
    else               tau = t - 3;
    const bool active = (tau >= 0) && (tau < TLEN);

    if (active) {
      f32x4 acc0 = {0.f, 0.f, 0.f, 0.f}, acc1 = {0.f, 0.f, 0.f, 0.f};

      if (grp == 0) {
        // A = x[t] rows (external dtype)
        const size_t abase = (size_t)(lane & 15) * (TLEN * H) + (size_t)tau * H + quad * 8;
        #pragma unroll
        for (int kk = 0; kk < 12; kk++) {
          short8 a0 = loadA8(x, isbf, abase + kk * 32);
          short8 a1 = loadA8(x, isbf, abase + (kk + 12) * 32);
          acc0 = __builtin_amdgcn_mfma_f32_16x16x32_bf16(a0, bfrag[kk],      acc0, 0, 0, 0);
          acc1 = __builtin_amdgcn_mfma_f32_16x16x32_bf16(a1, bfrag[kk + 12], acc1, 0, 0, 0);
        }
      } else {
        // A = h rows (internal bf16 always)
        const ushort* hsrc = (grp == 3) ? h2buf : h1buf;
        const ushort* abase = hsrc + (size_t)par * (BATCH * H) + (lane & 15) * H + quad * 8;
        #pragma unroll
        for (int kk = 0; kk < 12; kk++) {
          short8 a0 = *(const short8*)(abase + kk * 32);
          short8 a1 = *(const short8*)(abase + (kk + 12) * 32);
          acc0 = __builtin_amdgcn_mfma_f32_16x16x32_bf16(a0, bfrag[kk],      acc0, 0, 0, 0);
          acc1 = __builtin_amdgcn_mfma_f32_16x16x32_bf16(a1, bfrag[kk + 12], acc1, 0, 0, 0);
        }
      }
      f32x4 acc = acc0 + acc1;

      if (grp == 0 || grp == 2) {
        // raw gate-x slice -> global (fp32), consumed next tick(s)
        float* gxout = ((grp == 0) ? gx1buf : gx2buf) + (size_t)par * (BATCH * G3);
        #pragma unroll
        for (int i = 0; i < 4; i++) {
          int m = quad * 4 + i;
          gxout[(size_t)m * G3 + wgi * 96 + gfbase + col] = acc[i];
        }
      } else {
        // stage gh tile to LDS, then elementwise GRU combine
        #pragma unroll
        for (int i = 0; i < 4; i++)
          ghs[(gfbase + col) * 17 + quad * 4 + i] = acc[i];
        __syncthreads();

        const int opar = tau & 1;
        const float* gxin = ((grp == 1) ? gx1buf : gx2buf) + (size_t)opar * (BATCH * G3);
        ushort* hout = ((grp == 1) ? h1buf : h2buf) + (size_t)opar * (BATCH * H);

        for (int idx = tid; idx < BATCH * SLICE; idx += NTHR) {
          const int b = idx >> 5;
          const int j = idx & 31;
          const float* gxr = gxin + (size_t)b * G3 + wgi * 96;
          float rpre = gxr[j]      + bih_s[j]      + ghs[j * 17 + b]        + bhh_s[j];
          float zpre = gxr[32 + j] + bih_s[32 + j] + ghs[(32 + j) * 17 + b] + bhh_s[32 + j];
          float hn   = ghs[(64 + j) * 17 + b] + bhh_s[64 + j];
          float r = 1.0f / (1.0f + expf(-rpre));
          float z = 1.0f / (1.0f + expf(-zpre));
          float n = tanhf(gxr[64 + j] + bih_s[64 + j] + r * hn);
          float hnew = (1.0f - z) * n + z * hold[idx];
          hold[idx] = hnew;
          ushort hb = f2b(hnew);
          hout[(size_t)b * H + wgi * SLICE + j] = hb;
          if (grp == 3)
            y2[((size_t)b * TLEN + tau) * H + wgi * SLICE + j] = hb;
        }
      }
    }

    // ---- grid barrier (monotonic counter, agent scope) ----
    __syncthreads();
    target += NWG;
    if (tid == 0) {
      __threadfence();                       // release (L2 writeback)
      atomicAdd(cnt, 1u);                    // device-scope by default
      while (__hip_atomic_load(cnt, __ATOMIC_RELAXED, __HIP_MEMORY_SCOPE_AGENT) < target) {
        __builtin_amdgcn_s_sleep(1);
      }
      __threadfence();                       // acquire (L2 invalidate)
    }
    __syncthreads();
  }
}

// ---------------------------------------------------------------------------
// Final FC (768->512) + bias + exact GELU.  M=16384, N=512, K=768.
// ---------------------------------------------------------------------------
__global__ __launch_bounds__(256) void fc_kernel(
    const ushort* __restrict__ y2,     // [16384][768] bf16 (internal)
    const void* __restrict__ w_fc,     // [512][768]
    const void* __restrict__ b_fc,     // [512]
    const unsigned* __restrict__ dflag,
    void* __restrict__ out)            // [16384][512]
{
  const bool isbf = dflag[0] != 0u;
  const int wave = threadIdx.x >> 6;
  const int lane = threadIdx.x & 63;
  const int col  = lane & 15;
  const int quad = lane >> 4;
  const int m0 = blockIdx.x * 64 + wave * 16;
  const int n0 = blockIdx.y * 64;

  const ushort* arow = y2 + (size_t)(m0 + col) * H + quad * 8;
  const size_t bbase = (size_t)(n0 + col) * H + quad * 8;

  f32x4 acc[4];
  #pragma unroll
  for (int nt = 0; nt < 4; nt++) acc[nt] = (f32x4){0.f, 0.f, 0.f, 0.f};

  for (int kk = 0; kk < 24; kk++) {
    short8 a = *(const short8*)(arow + kk * 32);
    #pragma unroll
    for (int nt = 0; nt < 4; nt++) {
      short8 b = loadA8(w_fc, isbf, bbase + (size_t)nt * 16 * H + kk * 32);
      acc[nt] = __builtin_amdgcn_mfma_f32_16x16x32_bf16(a, b, acc[nt], 0, 0, 0);
    }
  }

  #pragma unroll
  for (int nt = 0; nt < 4; nt++) {
    #pragma unroll
    for (int i = 0; i < 4; i++) {
      int m = m0 + quad * 4 + i;
      int n = n0 + nt * 16 + col;
      float v = acc[nt][i] + loadS(b_fc, isbf, n);
      float g = 0.5f * v * (1.0f + erff(v * 0.70710678118654752f));
      if (isbf) ((ushort*)out)[(size_t)m * DOUT + n] = f2b(g);
      else      ((float*)out)[(size_t)m * DOUT + n] = g;
    }
  }
}

extern "C" void kernel_launch(void* const* d_in, const int* in_sizes, int n_in,
                              void* d_out, int out_size, void* d_ws, size_t ws_size,
                              hipStream_t stream) {
  const void* x    = d_in[0];
  const void* w_ih = d_in[1];
  const void* w_hh = d_in[2];
  const void* b_ih = d_in[3];
  const void* b_hh = d_in[4];
  const void* w_fc = d_in[5];
  const void* b_fc = d_in[6];

  char* ws = (char*)d_ws;
  // layout: [0,64) cnt | [64,128) dflag | [256,49408) h1 | [49408,98560) h2 |
  //         [98560,393472) gx1 | [393472,688384) gx2 | [688384, +25165824) y2
  unsigned int* cnt   = (unsigned int*)(ws);
  unsigned int* dflag = (unsigned int*)(ws + 64);
  ushort* h1buf = (ushort*)(ws + 256);
  ushort* h2buf = (ushort*)(ws + 49408);
  float*  gx1buf = (float*)(ws + 98560);
  float*  gx2buf = (float*)(ws + 393472);
  ushort* y2     = (ushort*)(ws + 688384);

  hipMemsetAsync(ws, 0, 98560, stream);   // cnt + dflag + h1 + h2 (both parities)
  scan_kernel<<<dim3(NWG), dim3(NTHR), 0, stream>>>(
      x, w_ih, w_hh, b_ih, b_hh, cnt, dflag, h1buf, h2buf, gx1buf, gx2buf, y2);
  fc_kernel<<<dim3(16384 / 64, DOUT / 64), dim3(256), 0, stream>>>(
      y2, w_fc, b_fc, dflag, (void*)d_out);
}

// Round 3
// 14420.514 us; speedup vs baseline: 1.2388x; 1.2388x over previous
//
#include <hip/hip_runtime.h>
#include <hip/hip_bf16.h>

#define H     768
#define G3    2304
#define BATCH 16
#define TLEN  1024
#define DOUT  512
#define SLICE 32
#define WPG   24      // workgroups per group (768/32)
#define NWG   96      // 4 groups * 24
#define NTHR  384     // 6 waves

typedef __attribute__((ext_vector_type(8))) short short8;
typedef __attribute__((ext_vector_type(4))) float f32x4;

union U8 { short8 s; unsigned u[4]; unsigned long long q[2]; };

__device__ __forceinline__ float b2f(ushort u) {
  union { unsigned int ui; float f; } v; v.ui = ((unsigned int)u) << 16; return v.f;
}
__device__ __forceinline__ ushort f2b(float f) {
  union { float f; unsigned int ui; } v; v.f = f;
  unsigned int u = v.ui;
  return (ushort)((u + 0x7fffu + ((u >> 16) & 1u)) >> 16);
}

// ---- agent-scope (cross-XCD coherent, cache-bypassing) relaxed accessors ----
__device__ __forceinline__ unsigned long long agent_ld64(const void* p) {
  return __hip_atomic_load((const unsigned long long*)p, __ATOMIC_RELAXED, __HIP_MEMORY_SCOPE_AGENT);
}
__device__ __forceinline__ unsigned agent_ld32(const void* p) {
  return __hip_atomic_load((const unsigned*)p, __ATOMIC_RELAXED, __HIP_MEMORY_SCOPE_AGENT);
}
__device__ __forceinline__ void agent_st32(void* p, unsigned v) {
  __hip_atomic_store((unsigned*)p, v, __ATOMIC_RELAXED, __HIP_MEMORY_SCOPE_AGENT);
}
__device__ __forceinline__ void agent_stf(void* p, float v) {
  __hip_atomic_store((float*)p, v, __ATOMIC_RELAXED, __HIP_MEMORY_SCOPE_AGENT);
}
// 8 bf16 (16B) fragment via two 64-bit agent loads
__device__ __forceinline__ short8 agent_ldH8(const ushort* p) {
  U8 u;
  u.q[0] = agent_ld64(p);
  u.q[1] = agent_ld64(p + 4);
  return u.s;
}

// 16-byte-granular load of 8 elements as bf16 fragment (plain/cached path).
__device__ __forceinline__ short8 loadA8(const void* base, bool bf, size_t eidx) {
  if (bf) return *(const short8*)((const ushort*)base + eidx);
  const uint4* f = (const uint4*)((const float*)base + eidx);
  uint4 lo = f[0];
  uint4 hi = f[1];
  U8 r;
  r.u[0] = __builtin_amdgcn_perm(lo.y, lo.x, 0x07060302);
  r.u[1] = __builtin_amdgcn_perm(lo.w, lo.z, 0x07060302);
  r.u[2] = __builtin_amdgcn_perm(hi.y, hi.x, 0x07060302);
  r.u[3] = __builtin_amdgcn_perm(hi.w, hi.z, 0x07060302);
  return r.s;
}
__device__ __forceinline__ short8 loadW8(const void* base, bool bf, size_t eidx) {
  if (bf) return *(const short8*)((const ushort*)base + eidx);
  const float* f = (const float*)base + eidx;
  short8 r;
  #pragma unroll
  for (int i = 0; i < 8; i++) r[i] = (short)f2b(f[i]);
  return r;
}
__device__ __forceinline__ float loadS(const void* p, bool bf, size_t i) {
  return bf ? b2f(((const ushort*)p)[i]) : ((const float*)p)[i];
}

__device__ __forceinline__ bool detect_bf16(const unsigned* xw, int tid, int nthr, int* sh) {
  if (tid == 0) *sh = 0;
  __syncthreads();
  int c = 0;
  for (int i = tid; i < 4096; i += nthr) {
    int e = (int)((xw[i] >> 7) & 0xFF);
    c += (e >= 110 && e <= 140) ? 1 : 0;
  }
  atomicAdd(sh, c);
  __syncthreads();
  return *sh > 2048;
}

// ---------------------------------------------------------------------------
// Persistent pipelined GRU scan — fence-free agent-scope comms + flag barrier.
// Groups: 0=GX1 (w_ih1 @ x[t]), 1=L1 (w_hh1 @ h1 + combine),
//         2=GX2 (w_ih2 @ h1),   3=GH2 (w_hh2 @ h2 + combine, writes y2)
// Tick t computes: gx1[t], h1[t-1], gx2[t-2], h2[t-3].  One barrier/tick.
// ---------------------------------------------------------------------------
__global__ __launch_bounds__(NTHR) void scan_kernel(
    const void* __restrict__ x,        // [16][1024][768]
    const void* __restrict__ w_ih,     // [2][2304][768]
    const void* __restrict__ w_hh,     // [2][2304][768]
    const void* __restrict__ b_ih,     // [2][2304]
    const void* __restrict__ b_hh,     // [2][2304]
    unsigned int* epoch,               // broadcast epoch (zeroed)
    unsigned int* flags,               // [NWG] per-WG arrival flags (zeroed)
    unsigned int* dflag,               // dtype flag out (for fc)
    ushort* h1buf,                     // [2][16][768] bf16 (zeroed)
    ushort* h2buf,                     // [2][16][768] bf16 (zeroed)
    float*  gx1buf,                    // [2][16][2304] f32
    float*  gx2buf,                    // [2][16][2304] f32
    ushort* y2)                        // [16][1024][768] bf16
{
  const int wg   = blockIdx.x;
  const int grp  = wg / WPG;           // 0..3
  const int wgi  = wg % WPG;           // 0..23 -> gate columns [wgi*32, wgi*32+32)
  const int tid  = threadIdx.x;
  const int wave = tid >> 6;           // 0..5
  const int lane = tid & 63;
  const int col  = lane & 15;
  const int quad = lane >> 4;          // 0..3

  __shared__ float ghs[96 * 17];       // gh slice [gate 0..95][batch], padded
  __shared__ float hold[BATCH * SLICE];// persistent fp32 h slice [b][j]
  __shared__ float bih_s[96], bhh_s[96];
  __shared__ int   detsh;

  const bool isbf = detect_bf16((const unsigned*)x, tid, NTHR, &detsh);
  if (tid == 0) dflag[0] = isbf ? 1u : 0u;

  for (int i = tid; i < BATCH * SLICE; i += NTHR) hold[i] = 0.0f;

  if (grp == 1 || grp == 3) {
    size_t boff = (grp == 3) ? (size_t)G3 : 0;
    for (int gf = tid; gf < 96; gf += NTHR) {
      size_t gidx = boff + (size_t)(gf >> 5) * H + wgi * SLICE + (gf & 31);
      bih_s[gf] = loadS(b_ih, isbf, gidx);
      bhh_s[gf] = loadS(b_hh, isbf, gidx);
    }
  }

  // ---- load this wave's B-fragments (16 gate rows x K=768) into registers --
  const void* Wmat = (grp == 0 || grp == 2) ? w_ih : w_hh;
  const size_t woff = (grp >= 2) ? (size_t)G3 * H : 0;
  const int gate   = wave >> 1;                       // 0=r,1=z,2=n
  const int gfbase = gate * SLICE + (wave & 1) * 16;  // within-wg flat gate base
  const int nrow   = gate * H + wgi * SLICE + (wave & 1) * 16 + col;
  const size_t wbase = woff + (size_t)nrow * H + quad * 8;

  short8 bfrag[24];
  #pragma unroll
  for (int kk = 0; kk < 24; kk++)
    bfrag[kk] = loadW8(Wmat, isbf, wbase + kk * 32);

  __syncthreads();

  for (int t = 0; t < TLEN + 3; t++) {
    const int par = t & 1;
    int tau;
    if      (grp == 0) tau = t;
    else if (grp == 1) tau = t - 1;
    else if (grp == 2) tau = t - 2;
    else               tau = t - 3;
    const bool active = (tau >= 0) && (tau < TLEN);

    if (active) {
      const int opar = tau & 1;
      const bool isL = (grp == 1 || grp == 3);
      const float* gxin = (grp == 1) ? (gx1buf + (size_t)opar * (BATCH * G3))
                        : (grp == 3) ? (gx2buf + (size_t)opar * (BATCH * G3)) : nullptr;

      // ---- early-issue combine-phase gx loads (produced last tick) ----
      unsigned long long gr01 = 0, gz01 = 0, gn01 = 0;
      int pb = 0, pj = 0;
      const bool pact = isL && (tid < BATCH * SLICE / 2);
      if (pact) {
        pb = tid >> 4;
        pj = (tid & 15) * 2;
        const float* gxr = gxin + (size_t)pb * G3 + wgi * 96;
        gr01 = agent_ld64(gxr + pj);
        gz01 = agent_ld64(gxr + 32 + pj);
        gn01 = agent_ld64(gxr + 64 + pj);
      }

      f32x4 acc0 = {0.f, 0.f, 0.f, 0.f}, acc1 = {0.f, 0.f, 0.f, 0.f};

      if (grp == 0) {
        // A = x[t] rows (plain cached loads; x is read-only)
        const size_t abase = (size_t)(lane & 15) * (TLEN * H) + (size_t)tau * H + quad * 8;
        #pragma unroll
        for (int kk = 0; kk < 12; kk++) {
          short8 a0 = loadA8(x, isbf, abase + kk * 32);
          short8 a1 = loadA8(x, isbf, abase + (kk + 12) * 32);
          acc0 = __builtin_amdgcn_mfma_f32_16x16x32_bf16(a0, bfrag[kk],      acc0, 0, 0, 0);
          acc1 = __builtin_amdgcn_mfma_f32_16x16x32_bf16(a1, bfrag[kk + 12], acc1, 0, 0, 0);
        }
      } else {
        // A = h rows (agent-scope coherent loads)
        const ushort* hsrc = (grp == 3) ? h2buf : h1buf;
        const ushort* abase = hsrc + (size_t)par * (BATCH * H) + (lane & 15) * H + quad * 8;
        #pragma unroll
        for (int kk = 0; kk < 12; kk++) {
          short8 a0 = agent_ldH8(abase + kk * 32);
          short8 a1 = agent_ldH8(abase + (kk + 12) * 32);
          acc0 = __builtin_amdgcn_mfma_f32_16x16x32_bf16(a0, bfrag[kk],      acc0, 0, 0, 0);
          acc1 = __builtin_amdgcn_mfma_f32_16x16x32_bf16(a1, bfrag[kk + 12], acc1, 0, 0, 0);
        }
      }
      f32x4 acc = acc0 + acc1;

      if (grp == 0 || grp == 2) {
        // raw gate-x slice -> agent stores (consumed next tick)
        float* gxout = ((grp == 0) ? gx1buf : gx2buf) + (size_t)par * (BATCH * G3);
        #pragma unroll
        for (int i = 0; i < 4; i++) {
          int m = quad * 4 + i;
          agent_stf(&gxout[(size_t)m * G3 + wgi * 96 + gfbase + col], acc[i]);
        }
      } else {
        // stage gh tile to LDS, then elementwise GRU combine (pairs of j)
        #pragma unroll
        for (int i = 0; i < 4; i++)
          ghs[(gfbase + col) * 17 + quad * 4 + i] = acc[i];
        __syncthreads();

        if (pact) {
          union { unsigned long long q; float f[2]; } ur, uz, un;
          ur.q = gr01; uz.q = gz01; un.q = gn01;
          ushort* hout = ((grp == 1) ? h1buf : h2buf) + (size_t)opar * (BATCH * H);
          unsigned hpack = 0;
          #pragma unroll
          for (int s = 0; s < 2; s++) {
            const int j = pj + s;
            float rpre = ur.f[s] + bih_s[j]      + ghs[j * 17 + pb]        + bhh_s[j];
            float zpre = uz.f[s] + bih_s[32 + j] + ghs[(32 + j) * 17 + pb] + bhh_s[32 + j];
            float hn   = ghs[(64 + j) * 17 + pb] + bhh_s[64 + j];
            float r = 1.0f / (1.0f + expf(-rpre));
            float z = 1.0f / (1.0f + expf(-zpre));
            float n = tanhf(un.f[s] + bih_s[64 + j] + r * hn);
            float hnew = (1.0f - z) * n + z * hold[pb * SLICE + j];
            hold[pb * SLICE + j] = hnew;
            hpack |= ((unsigned)f2b(hnew)) << (16 * s);
          }
          agent_st32(&hout[(size_t)pb * H + wgi * SLICE + pj], hpack);
          if (grp == 3)
            *(unsigned*)&y2[((size_t)pb * TLEN + tau) * H + wgi * SLICE + pj] = hpack;
        }
      }
    }

    // ---- fence-free flag-tree barrier ----
    __syncthreads();                       // drains vmcnt: all comms stores visible
    const unsigned tgt = (unsigned)(t + 1);
    if (tid == 0) agent_st32(&flags[wg], tgt);
    if (wg == 0) {
      if (tid < NWG) {
        while (agent_ld32(&flags[tid]) < tgt) __builtin_amdgcn_s_sleep(1);
      }
      __syncthreads();
      if (tid == 0) agent_st32(epoch, tgt);
    } else {
      if (tid == 0) {
        while (agent_ld32(epoch) < tgt) __builtin_amdgcn_s_sleep(1);
      }
    }
    __syncthreads();
  }
}

// ---------------------------------------------------------------------------
// Final FC (768->512) + bias + exact GELU.  M=16384, N=512, K=768.
// ---------------------------------------------------------------------------
__global__ __launch_bounds__(256) void fc_kernel(
    const ushort* __restrict__ y2,     // [16384][768] bf16 (internal)
    const void* __restrict__ w_fc,     // [512][768]
    const void* __restrict__ b_fc,     // [512]
    const unsigned* __restrict__ dflag,
    void* __restrict__ out)            // [16384][512]
{
  const bool isbf = dflag[0] != 0u;
  const int wave = threadIdx.x >> 6;
  const int lane = threadIdx.x & 63;
  const int col  = lane & 15;
  const int quad = lane >> 4;
  const int m0 = blockIdx.x * 64 + wave * 16;
  const int n0 = blockIdx.y * 64;

  const ushort* arow = y2 + (size_t)(m0 + col) * H + quad * 8;
  const size_t bbase = (size_t)(n0 + col) * H + quad * 8;

  f32x4 acc[4];
  #pragma unroll
  for (int nt = 0; nt < 4; nt++) acc[nt] = (f32x4){0.f, 0.f, 0.f, 0.f};

  for (int kk = 0; kk < 24; kk++) {
    short8 a = *(const short8*)(arow + kk * 32);
    #pragma unroll
    for (int nt = 0; nt < 4; nt++) {
      short8 b = loadA8(w_fc, isbf, bbase + (size_t)nt * 16 * H + kk * 32);
      acc[nt] = __builtin_amdgcn_mfma_f32_16x16x32_bf16(a, b, acc[nt], 0, 0, 0);
    }
  }

  #pragma unroll
  for (int nt = 0; nt < 4; nt++) {
    #pragma unroll
    for (int i = 0; i < 4; i++) {
      int m = m0 + quad * 4 + i;
      int n = n0 + nt * 16 + col;
      float v = acc[nt][i] + loadS(b_fc, isbf, n);
      float g = 0.5f * v * (1.0f + erff(v * 0.70710678118654752f));
      if (isbf) ((ushort*)out)[(size_t)m * DOUT + n] = f2b(g);
      else      ((float*)out)[(size_t)m * DOUT + n] = g;
    }
  }
}

extern "C" void kernel_launch(void* const* d_in, const int* in_sizes, int n_in,
                              void* d_out, int out_size, void* d_ws, size_t ws_size,
                              hipStream_t stream) {
  const void* x    = d_in[0];
  const void* w_ih = d_in[1];
  const void* w_hh = d_in[2];
  const void* b_ih = d_in[3];
  const void* b_hh = d_in[4];
  const void* w_fc = d_in[5];
  const void* b_fc = d_in[6];

  char* ws = (char*)d_ws;
  // layout: [0,4) epoch | [64,68) dflag | [128,512) flags[96] |
  //         [512,49664) h1 | [49664,98816) h2 | [98816,393728) gx1 |
  //         [393728,688640) gx2 | [688640,25854464) y2
  unsigned int* epoch = (unsigned int*)(ws);
  unsigned int* dflag = (unsigned int*)(ws + 64);
  unsigned int* flags = (unsigned int*)(ws + 128);
  ushort* h1buf  = (ushort*)(ws + 512);
  ushort* h2buf  = (ushort*)(ws + 49664);
  float*  gx1buf = (float*)(ws + 98816);
  float*  gx2buf = (float*)(ws + 393728);
  ushort* y2     = (ushort*)(ws + 688640);

  hipMemsetAsync(ws, 0, 98816, stream);   // epoch + dflag + flags + h1 + h2
  scan_kernel<<<dim3(NWG), dim3(NTHR), 0, stream>>>(
      x, w_ih, w_hh, b_ih, b_hh, epoch, flags, dflag,
      h1buf, h2buf, gx1buf, gx2buf, y2);
  fc_kernel<<<dim3(16384 / 64, DOUT / 64), dim3(256), 0, stream>>>(
      y2, w_fc, b_fc, dflag, (void*)d_out);
}

// Round 4
// 4485.838 us; speedup vs baseline: 3.9824x; 3.2147x over previous
//
#include <hip/hip_runtime.h>
#include <hip/hip_bf16.h>

#define H     768
#define HPAD  776     // LDS row stride (bf16 elems): +8 keeps 16B align, spreads banks
#define G3    2304
#define BATCH 16
#define TLEN  1024
#define DOUT  512
#define SLICE 32
#define WPG   24      // workgroups per group (768/32)
#define NWG   96      // 4 groups * 24
#define NTHR  384     // 6 waves

typedef __attribute__((ext_vector_type(8))) short short8;
typedef __attribute__((ext_vector_type(4))) float f32x4;

union U8 { short8 s; unsigned u[4]; unsigned long long q[2]; uint4 v4; };

__device__ __forceinline__ float b2f(ushort u) {
  union { unsigned int ui; float f; } v; v.ui = ((unsigned int)u) << 16; return v.f;
}
__device__ __forceinline__ ushort f2b(float f) {
  union { float f; unsigned int ui; } v; v.f = f;
  unsigned int u = v.ui;
  return (ushort)((u + 0x7fffu + ((u >> 16) & 1u)) >> 16);
}

// ---- agent-scope (cross-XCD coherent, cache-bypassing) relaxed accessors ----
__device__ __forceinline__ unsigned long long agent_ld64(const void* p) {
  return __hip_atomic_load((const unsigned long long*)p, __ATOMIC_RELAXED, __HIP_MEMORY_SCOPE_AGENT);
}
__device__ __forceinline__ unsigned agent_ld32(const void* p) {
  return __hip_atomic_load((const unsigned*)p, __ATOMIC_RELAXED, __HIP_MEMORY_SCOPE_AGENT);
}
__device__ __forceinline__ void agent_st32(void* p, unsigned v) {
  __hip_atomic_store((unsigned*)p, v, __ATOMIC_RELAXED, __HIP_MEMORY_SCOPE_AGENT);
}
__device__ __forceinline__ void agent_st64(void* p, unsigned long long v) {
  __hip_atomic_store((unsigned long long*)p, v, __ATOMIC_RELAXED, __HIP_MEMORY_SCOPE_AGENT);
}

// 16-byte-granular load of 8 elements as bf16 fragment (plain/cached path).
__device__ __forceinline__ short8 loadA8(const void* base, bool bf, size_t eidx) {
  if (bf) return *(const short8*)((const ushort*)base + eidx);
  const uint4* f = (const uint4*)((const float*)base + eidx);
  uint4 lo = f[0];
  uint4 hi = f[1];
  U8 r;
  r.u[0] = __builtin_amdgcn_perm(lo.y, lo.x, 0x07060302);
  r.u[1] = __builtin_amdgcn_perm(lo.w, lo.z, 0x07060302);
  r.u[2] = __builtin_amdgcn_perm(hi.y, hi.x, 0x07060302);
  r.u[3] = __builtin_amdgcn_perm(hi.w, hi.z, 0x07060302);
  return r.s;
}
__device__ __forceinline__ short8 loadW8(const void* base, bool bf, size_t eidx) {
  if (bf) return *(const short8*)((const ushort*)base + eidx);
  const float* f = (const float*)base + eidx;
  short8 r;
  #pragma unroll
  for (int i = 0; i < 8; i++) r[i] = (short)f2b(f[i]);
  return r;
}
__device__ __forceinline__ float loadS(const void* p, bool bf, size_t i) {
  return bf ? b2f(((const ushort*)p)[i]) : ((const float*)p)[i];
}

__device__ __forceinline__ bool detect_bf16(const unsigned* xw, int tid, int nthr, int* sh) {
  if (tid == 0) *sh = 0;
  __syncthreads();
  int c = 0;
  for (int i = tid; i < 4096; i += nthr) {
    int e = (int)((xw[i] >> 7) & 0xFF);
    c += (e >= 110 && e <= 140) ? 1 : 0;
  }
  atomicAdd(sh, c);
  __syncthreads();
  return *sh > 2048;
}

// ---------------------------------------------------------------------------
// Persistent pipelined GRU scan.
// Groups: 0=GX1 (w_ih1 @ x[t]), 1=L1 (w_hh1 @ h1 + combine),
//         2=GX2 (w_ih2 @ h1),   3=GH2 (w_hh2 @ h2 + combine, writes y2)
// Tick t computes: gx1[t], h1[t-1], gx2[t-2], h2[t-3].  One barrier/tick.
// Barrier: padded per-WG flags (1 line each) -> WG0 polls 96 lines in
// parallel -> 16 padded epoch replicas (<=6 pollers/line).  All comms via
// relaxed agent-scope ops; __syncthreads (vmcnt drain) orders store->flag.
// ---------------------------------------------------------------------------
__global__ __launch_bounds__(NTHR) void scan_kernel(
    const void* __restrict__ x,        // [16][1024][768]
    const void* __restrict__ w_ih,     // [2][2304][768]
    const void* __restrict__ w_hh,     // [2][2304][768]
    const void* __restrict__ b_ih,     // [2][2304]
    const void* __restrict__ b_hh,     // [2][2304]
    unsigned int* epoch,               // [16*32] padded replicas (zeroed)
    unsigned int* flags,               // [96*32] padded per-WG flags (zeroed)
    unsigned int* dflag,               // dtype flag out (for fc)
    ushort* h1buf,                     // [2][16][768] bf16 (zeroed)
    ushort* h2buf,                     // [2][16][768] bf16 (zeroed)
    float*  gxbuf1,                    // [2][24][16][96] f32 (per-WG slices)
    float*  gxbuf2,                    // [2][24][16][96] f32
    ushort* y2)                        // [16][1024][768] bf16
{
  const int wg   = blockIdx.x;
  const int grp  = wg / WPG;           // 0..3
  const int wgi  = wg % WPG;           // 0..23 -> gate columns [wgi*32, wgi*32+32)
  const int tid  = threadIdx.x;
  const int wave = tid >> 6;           // 0..5
  const int lane = tid & 63;
  const int quad = lane >> 4;          // 0..3

  __shared__ ushort h_lds[BATCH * HPAD];   // staged A tile (x or h), 24.8 KB
  __shared__ float ghs[96 * 17];           // MFMA C tile [gate-col][batch]
  __shared__ float hold[BATCH * SLICE];    // persistent fp32 h slice
  __shared__ float bih_s[96], bhh_s[96];
  __shared__ int   detsh;

  const bool isbf = detect_bf16((const unsigned*)x, tid, NTHR, &detsh);
  if (tid == 0) dflag[0] = isbf ? 1u : 0u;

  for (int i = tid; i < BATCH * SLICE; i += NTHR) hold[i] = 0.0f;

  if (grp == 1 || grp == 3) {
    size_t boff = (grp == 3) ? (size_t)G3 : 0;
    for (int gf = tid; gf < 96; gf += NTHR) {
      size_t gidx = boff + (size_t)(gf >> 5) * H + wgi * SLICE + (gf & 31);
      bih_s[gf] = loadS(b_ih, isbf, gidx);
      bhh_s[gf] = loadS(b_hh, isbf, gidx);
    }
  }

  // ---- load this wave's B-fragments (16 gate rows x K=768) into registers --
  const void* Wmat = (grp == 0 || grp == 2) ? w_ih : w_hh;
  const size_t woff = (grp >= 2) ? (size_t)G3 * H : 0;
  const int gate   = wave >> 1;                       // 0=r,1=z,2=n
  const int gfbase = gate * SLICE + (wave & 1) * 16;  // within-wg flat gate base
  const int nrow   = gate * H + wgi * SLICE + (wave & 1) * 16 + (lane & 15);
  const size_t wbase = woff + (size_t)nrow * H + quad * 8;

  short8 bfrag[24];
  #pragma unroll
  for (int kk = 0; kk < 24; kk++)
    bfrag[kk] = loadW8(Wmat, isbf, wbase + kk * 32);

  // staging decomposition: thread -> (row b, 32-elem segment)
  const int sb  = tid / 24;            // 0..15
  const int seg = tid % 24;            // 0..23 (each 32 elems = 64B)

  // combine decomposition: 256 threads, pairs of columns
  const int pb = tid >> 4;             // batch
  const int pj = (tid & 15) * 2;       // column pair
  const bool pact = (tid < BATCH * SLICE / 2);

  __syncthreads();

  for (int t = 0; t < TLEN + 3; t++) {
    const int par = t & 1;
    int tau;
    if      (grp == 0) tau = t;
    else if (grp == 1) tau = t - 1;
    else if (grp == 2) tau = t - 2;
    else               tau = t - 3;
    const bool active = (tau >= 0) && (tau < TLEN);
    const bool isL = (grp == 1 || grp == 3);

    if (active) {
      const int opar = tau & 1;

      // ---- early-issue combine-phase gx loads (produced in a prior tick) --
      unsigned long long gr01 = 0, gz01 = 0, gn01 = 0;
      const float* gxin = nullptr;
      if (isL) {
        gxin = ((grp == 1) ? gxbuf1 : gxbuf2) + ((size_t)(opar * WPG + wgi) * BATCH) * 96;
        if (pact) {
          const float* gxr = gxin + (size_t)pb * 96;
          gr01 = agent_ld64(gxr + pj);
          gz01 = agent_ld64(gxr + 32 + pj);
          gn01 = agent_ld64(gxr + 64 + pj);
        }
      }

      // ---- stage A tile (16 x 768) into LDS ----
      if (grp == 0) {
        // x[t] rows, plain cached loads (handles fp32 fallback too)
        const size_t srcbase = ((size_t)sb * TLEN + tau) * H + seg * 32;
        #pragma unroll
        for (int i = 0; i < 4; i++) {
          short8 v = loadA8(x, isbf, srcbase + i * 8);
          *(short8*)&h_lds[sb * HPAD + seg * 32 + i * 8] = v;
        }
      } else {
        const ushort* hsrc = ((grp == 3) ? h2buf : h1buf) + (size_t)par * (BATCH * H);
        const ushort* src = hsrc + (size_t)sb * H + seg * 32;
        U8 a, b;
        a.q[0] = agent_ld64(src +  0); a.q[1] = agent_ld64(src +  4);
        b.q[0] = agent_ld64(src +  8); b.q[1] = agent_ld64(src + 12);
        U8 c, d;
        c.q[0] = agent_ld64(src + 16); c.q[1] = agent_ld64(src + 20);
        d.q[0] = agent_ld64(src + 24); d.q[1] = agent_ld64(src + 28);
        ushort* dst = &h_lds[sb * HPAD + seg * 32];
        *(uint4*)(dst + 0)  = a.v4;
        *(uint4*)(dst + 8)  = b.v4;
        *(uint4*)(dst + 16) = c.v4;
        *(uint4*)(dst + 24) = d.v4;
      }
      __syncthreads();

      // ---- MFMA: A from LDS, B from registers ----
      const ushort* arow = &h_lds[(lane & 15) * HPAD + quad * 8];
      f32x4 acc0 = {0.f, 0.f, 0.f, 0.f}, acc1 = {0.f, 0.f, 0.f, 0.f};
      #pragma unroll
      for (int kk = 0; kk < 12; kk++) {
        short8 a0 = *(const short8*)(arow + kk * 32);
        short8 a1 = *(const short8*)(arow + (kk + 12) * 32);
        acc0 = __builtin_amdgcn_mfma_f32_16x16x32_bf16(a0, bfrag[kk],      acc0, 0, 0, 0);
        acc1 = __builtin_amdgcn_mfma_f32_16x16x32_bf16(a1, bfrag[kk + 12], acc1, 0, 0, 0);
      }
      f32x4 acc = acc0 + acc1;

      // ---- stage C tile to LDS ----
      #pragma unroll
      for (int i = 0; i < 4; i++)
        ghs[(gfbase + (lane & 15)) * 17 + quad * 4 + i] = acc[i];
      __syncthreads();

      if (!isL) {
        // pack gx slice [16][96] f32 -> 8B agent stores
        float* gxout = ((grp == 0) ? gxbuf1 : gxbuf2) + ((size_t)(par * WPG + wgi) * BATCH) * 96;
        const int m  = tid / 24;
        const int c4 = (tid % 24) * 4;
        union { unsigned long long q; float f[2]; } p0, p1;
        p0.f[0] = ghs[(c4 + 0) * 17 + m];
        p0.f[1] = ghs[(c4 + 1) * 17 + m];
        p1.f[0] = ghs[(c4 + 2) * 17 + m];
        p1.f[1] = ghs[(c4 + 3) * 17 + m];
        agent_st64(gxout + (size_t)m * 96 + c4,     p0.q);
        agent_st64(gxout + (size_t)m * 96 + c4 + 2, p1.q);
      } else if (pact) {
        union { unsigned long long q; float f[2]; } ur, uz, un;
        ur.q = gr01; uz.q = gz01; un.q = gn01;
        ushort* hout = ((grp == 1) ? h1buf : h2buf) + (size_t)opar * (BATCH * H);
        unsigned hpack = 0;
        #pragma unroll
        for (int s = 0; s < 2; s++) {
          const int j = pj + s;
          float rpre = ur.f[s] + bih_s[j]      + ghs[j * 17 + pb]        + bhh_s[j];
          float zpre = uz.f[s] + bih_s[32 + j] + ghs[(32 + j) * 17 + pb] + bhh_s[32 + j];
          float hn   = ghs[(64 + j) * 17 + pb] + bhh_s[64 + j];
          float r = 1.0f / (1.0f + expf(-rpre));
          float z = 1.0f / (1.0f + expf(-zpre));
          float n = tanhf(un.f[s] + bih_s[64 + j] + r * hn);
          float hnew = (1.0f - z) * n + z * hold[pb * SLICE + j];
          hold[pb * SLICE + j] = hnew;
          hpack |= ((unsigned)f2b(hnew)) << (16 * s);
        }
        agent_st32(&hout[(size_t)pb * H + wgi * SLICE + pj], hpack);
        if (grp == 3)
          *(unsigned*)&y2[((size_t)pb * TLEN + tau) * H + wgi * SLICE + pj] = hpack;
      }
    }

    // ---- barrier: padded flags -> WG0 gathers -> padded epoch replicas ----
    __syncthreads();                       // drains vmcnt: comms stores visible
    const unsigned tgt = (unsigned)(t + 1);
    if (tid == 0) agent_st32(&flags[wg * 32], tgt);
    if (wg == 0) {
      if (tid < NWG) {                     // lanes 0..95 (waves 0-1), 1 line each
        while (agent_ld32(&flags[tid * 32]) < tgt) __builtin_amdgcn_s_sleep(2);
      }
      __syncthreads();
      if (tid < 16) agent_st32(&epoch[tid * 32], tgt);
    } else {
      if (tid == 0) {
        while (agent_ld32(&epoch[(wg & 15) * 32]) < tgt) __builtin_amdgcn_s_sleep(2);
      }
    }
    __syncthreads();
  }
}

// ---------------------------------------------------------------------------
// Final FC (768->512) + bias + exact GELU.  M=16384, N=512, K=768.
// ---------------------------------------------------------------------------
__global__ __launch_bounds__(256) void fc_kernel(
    const ushort* __restrict__ y2,     // [16384][768] bf16 (internal)
    const void* __restrict__ w_fc,     // [512][768]
    const void* __restrict__ b_fc,     // [512]
    const unsigned* __restrict__ dflag,
    void* __restrict__ out)            // [16384][512]
{
  const bool isbf = dflag[0] != 0u;
  const int wave = threadIdx.x >> 6;
  const int lane = threadIdx.x & 63;
  const int col  = lane & 15;
  const int quad = lane >> 4;
  const int m0 = blockIdx.x * 64 + wave * 16;
  const int n0 = blockIdx.y * 64;

  const ushort* arow = y2 + (size_t)(m0 + col) * H + quad * 8;
  const size_t bbase = (size_t)(n0 + col) * H + quad * 8;

  f32x4 acc[4];
  #pragma unroll
  for (int nt = 0; nt < 4; nt++) acc[nt] = (f32x4){0.f, 0.f, 0.f, 0.f};

  for (int kk = 0; kk < 24; kk++) {
    short8 a = *(const short8*)(arow + kk * 32);
    #pragma unroll
    for (int nt = 0; nt < 4; nt++) {
      short8 b = loadA8(w_fc, isbf, bbase + (size_t)nt * 16 * H + kk * 32);
      acc[nt] = __builtin_amdgcn_mfma_f32_16x16x32_bf16(a, b, acc[nt], 0, 0, 0);
    }
  }

  #pragma unroll
  for (int nt = 0; nt < 4; nt++) {
    #pragma unroll
    for (int i = 0; i < 4; i++) {
      int m = m0 + quad * 4 + i;
      int n = n0 + nt * 16 + col;
      float v = acc[nt][i] + loadS(b_fc, isbf, n);
      float g = 0.5f * v * (1.0f + erff(v * 0.70710678118654752f));
      if (isbf) ((ushort*)out)[(size_t)m * DOUT + n] = f2b(g);
      else      ((float*)out)[(size_t)m * DOUT + n] = g;
    }
  }
}

extern "C" void kernel_launch(void* const* d_in, const int* in_sizes, int n_in,
                              void* d_out, int out_size, void* d_ws, size_t ws_size,
                              hipStream_t stream) {
  const void* x    = d_in[0];
  const void* w_ih = d_in[1];
  const void* w_hh = d_in[2];
  const void* b_ih = d_in[3];
  const void* b_hh = d_in[4];
  const void* w_fc = d_in[5];
  const void* b_fc = d_in[6];

  char* ws = (char*)d_ws;
  // layout: [0,2048) epoch[16 lines] | [4096,16384) flags[96 lines] |
  //         [20480,20484) dflag | [24576,73728) h1 | [73728,122880) h2 |
  //         [122880,417792) gx1 | [417792,712704) gx2 | [712704,25878528) y2
  unsigned int* epoch = (unsigned int*)(ws);
  unsigned int* flags = (unsigned int*)(ws + 4096);
  unsigned int* dflag = (unsigned int*)(ws + 20480);
  ushort* h1buf  = (ushort*)(ws + 24576);
  ushort* h2buf  = (ushort*)(ws + 73728);
  float*  gxbuf1 = (float*)(ws + 122880);
  float*  gxbuf2 = (float*)(ws + 417792);
  ushort* y2     = (ushort*)(ws + 712704);

  hipMemsetAsync(ws, 0, 122880, stream);  // epoch + flags + dflag + h1 + h2
  scan_kernel<<<dim3(NWG), dim3(NTHR), 0, stream>>>(
      x, w_ih, w_hh, b_ih, b_hh, epoch, flags, dflag,
      h1buf, h2buf, gxbuf1, gxbuf2, y2);
  fc_kernel<<<dim3(16384 / 64, DOUT / 64), dim3(256), 0, stream>>>(
      y2, w_fc, b_fc, dflag, (void*)d_out);
}

// Round 5
// 4087.102 us; speedup vs baseline: 4.3709x; 1.0976x over previous
//
#include <hip/hip_runtime.h>
#include <hip/hip_bf16.h>

#define H     768
#define HPAD  776     // LDS row stride (bf16 elems): +8 keeps 16B align, spreads banks
#define G3    2304
#define BATCH 16
#define TLEN  1024
#define DOUT  512
#define SLICE 32
#define WPG   24      // workgroups per group (768/32)
#define NWG   96      // 4 groups * 24
#define NTHR  384     // 6 waves

typedef __attribute__((ext_vector_type(8))) short short8;
typedef __attribute__((ext_vector_type(4))) float f32x4;

union U8 { short8 s; unsigned u[4]; unsigned long long q[2]; uint4 v4; };

__device__ __forceinline__ float b2f(ushort u) {
  union { unsigned int ui; float f; } v; v.ui = ((unsigned int)u) << 16; return v.f;
}
__device__ __forceinline__ ushort f2b(float f) {
  union { float f; unsigned int ui; } v; v.f = f;
  unsigned int u = v.ui;
  return (ushort)((u + 0x7fffu + ((u >> 16) & 1u)) >> 16);
}

// ---- agent-scope (cross-XCD coherent, cache-bypassing) relaxed accessors ----
__device__ __forceinline__ unsigned long long agent_ld64(const void* p) {
  return __hip_atomic_load((const unsigned long long*)p, __ATOMIC_RELAXED, __HIP_MEMORY_SCOPE_AGENT);
}
__device__ __forceinline__ unsigned agent_ld32(const void* p) {
  return __hip_atomic_load((const unsigned*)p, __ATOMIC_RELAXED, __HIP_MEMORY_SCOPE_AGENT);
}
__device__ __forceinline__ void agent_st32(void* p, unsigned v) {
  __hip_atomic_store((unsigned*)p, v, __ATOMIC_RELAXED, __HIP_MEMORY_SCOPE_AGENT);
}
__device__ __forceinline__ void agent_st64(void* p, unsigned long long v) {
  __hip_atomic_store((unsigned long long*)p, v, __ATOMIC_RELAXED, __HIP_MEMORY_SCOPE_AGENT);
}

// 16-byte-granular load of 8 elements as bf16 fragment (plain/cached path).
__device__ __forceinline__ short8 loadA8(const void* base, bool bf, size_t eidx) {
  if (bf) return *(const short8*)((const ushort*)base + eidx);
  const uint4* f = (const uint4*)((const float*)base + eidx);
  uint4 lo = f[0];
  uint4 hi = f[1];
  U8 r;
  r.u[0] = __builtin_amdgcn_perm(lo.y, lo.x, 0x07060302);
  r.u[1] = __builtin_amdgcn_perm(lo.w, lo.z, 0x07060302);
  r.u[2] = __builtin_amdgcn_perm(hi.y, hi.x, 0x07060302);
  r.u[3] = __builtin_amdgcn_perm(hi.w, hi.z, 0x07060302);
  return r.s;
}
__device__ __forceinline__ short8 loadW8(const void* base, bool bf, size_t eidx) {
  if (bf) return *(const short8*)((const ushort*)base + eidx);
  const float* f = (const float*)base + eidx;
  short8 r;
  #pragma unroll
  for (int i = 0; i < 8; i++) r[i] = (short)f2b(f[i]);
  return r;
}
__device__ __forceinline__ float loadS(const void* p, bool bf, size_t i) {
  return bf ? b2f(((const ushort*)p)[i]) : ((const float*)p)[i];
}

__device__ __forceinline__ bool detect_bf16(const unsigned* xw, int tid, int nthr, int* sh) {
  if (tid == 0) *sh = 0;
  __syncthreads();
  int c = 0;
  for (int i = tid; i < 4096; i += nthr) {
    int e = (int)((xw[i] >> 7) & 0xFF);
    c += (e >= 110 && e <= 140) ? 1 : 0;
  }
  atomicAdd(sh, c);
  __syncthreads();
  return *sh > 2048;
}

// flag line: flags[((grp*WPG + wgi)*4 + rep)*32], 128B apart
__device__ __forceinline__ unsigned* flagp(unsigned* flags, int grp, int wgi, int rep) {
  return flags + (((grp * WPG + wgi) * 4 + rep) * 32);
}

// ---------------------------------------------------------------------------
// Persistent pipelined GRU scan — direct producer->consumer dependency flags.
// Groups: 0=GX1 (w_ih1 @ x[t]), 1=L1 (w_hh1 @ h1 + combine),
//         2=GX2 (w_ih2 @ h1),   3=GH2 (w_hh2 @ h2 + combine, writes y2)
// Tick t computes: gx1[t], h1[t-1], gx2[t-2], h2[t-3].
// Wait-before-tick-t (flags >= t; flag value = ticks completed):
//   GX1 i: {L1 i}                      (gx1 parity consumed)
//   L1  i: {GX1 i} + L1 all + GX2 all  (gx ready, h1 ready, h1 parity safe)
//   GX2 i: L1 all + {GH2 i}            (h1 ready, gx2 parity consumed)
//   GH2 i: {GX2 i} + GH2 all           (gx ready, h2 ready)
// Each flag has 4 padded replicas partitioned by reader class (<=24 pollers
// per line).  Flag posted after __syncthreads (vmcnt drain) => data visible.
// ---------------------------------------------------------------------------
__global__ __launch_bounds__(NTHR) void scan_kernel(
    const void* __restrict__ x,        // [16][1024][768]
    const void* __restrict__ w_ih,     // [2][2304][768]
    const void* __restrict__ w_hh,     // [2][2304][768]
    const void* __restrict__ b_ih,     // [2][2304]
    const void* __restrict__ b_hh,     // [2][2304]
    unsigned int* flags,               // [4][24][4][32] padded flags (zeroed)
    unsigned int* dflag,               // dtype flag out (for fc)
    ushort* h1buf,                     // [2][16][768] bf16 (zeroed)
    ushort* h2buf,                     // [2][16][768] bf16 (zeroed)
    float*  gxbuf1,                    // [2][24][16][96] f32 (per-WG slices)
    float*  gxbuf2,                    // [2][24][16][96] f32
    ushort* y2)                        // [16][1024][768] bf16
{
  const int wg   = blockIdx.x;
  const int grp  = wg / WPG;           // 0..3
  const int wgi  = wg % WPG;           // 0..23 -> gate columns [wgi*32, wgi*32+32)
  const int tid  = threadIdx.x;
  const int wave = tid >> 6;           // 0..5
  const int lane = tid & 63;
  const int quad = lane >> 4;          // 0..3

  __shared__ ushort h_lds[BATCH * HPAD];   // staged A tile (x or h), 24.8 KB
  __shared__ float ghs[96 * 17];           // MFMA C tile [gate-col][batch]
  __shared__ float hold[BATCH * SLICE];    // persistent fp32 h slice
  __shared__ float bih_s[96], bhh_s[96];
  __shared__ int   detsh;

  const bool isbf = detect_bf16((const unsigned*)x, tid, NTHR, &detsh);
  if (tid == 0) dflag[0] = isbf ? 1u : 0u;

  for (int i = tid; i < BATCH * SLICE; i += NTHR) hold[i] = 0.0f;

  if (grp == 1 || grp == 3) {
    size_t boff = (grp == 3) ? (size_t)G3 : 0;
    for (int gf = tid; gf < 96; gf += NTHR) {
      size_t gidx = boff + (size_t)(gf >> 5) * H + wgi * SLICE + (gf & 31);
      bih_s[gf] = loadS(b_ih, isbf, gidx);
      bhh_s[gf] = loadS(b_hh, isbf, gidx);
    }
  }

  // ---- per-lane poll pointer (wave 0 only) ----
  // replica assignment: r0 = same-group readers, r1 = partner (1 WG),
  // r2 = cross-group-all readers.
  const unsigned* pollp = nullptr;
  if (wave == 0) {
    if (grp == 0) {
      if (lane == 0) pollp = flagp(flags, 1, wgi, 1);
    } else if (grp == 1) {
      if      (lane == 0)  pollp = flagp(flags, 0, wgi, 1);
      else if (lane <= 24) pollp = flagp(flags, 1, lane - 1, 0);
      else if (lane <= 48) pollp = flagp(flags, 2, lane - 25, 2);
    } else if (grp == 2) {
      if      (lane < 24)  pollp = flagp(flags, 1, lane, 2);
      else if (lane == 24) pollp = flagp(flags, 3, wgi, 1);
    } else {
      if      (lane == 0)  pollp = flagp(flags, 2, wgi, 1);
      else if (lane <= 24) pollp = flagp(flags, 3, lane - 1, 0);
    }
  }

  // ---- load this wave's B-fragments (16 gate rows x K=768) into registers --
  const void* Wmat = (grp == 0 || grp == 2) ? w_ih : w_hh;
  const size_t woff = (grp >= 2) ? (size_t)G3 * H : 0;
  const int gate   = wave >> 1;                       // 0=r,1=z,2=n
  const int gfbase = gate * SLICE + (wave & 1) * 16;  // within-wg flat gate base
  const int nrow   = gate * H + wgi * SLICE + (wave & 1) * 16 + (lane & 15);
  const size_t wbase = woff + (size_t)nrow * H + quad * 8;

  short8 bfrag[24];
  #pragma unroll
  for (int kk = 0; kk < 24; kk++)
    bfrag[kk] = loadW8(Wmat, isbf, wbase + kk * 32);

  // staging decomposition: thread -> (row b, 32-elem segment)
  const int sb  = tid / 24;            // 0..15
  const int seg = tid % 24;            // 0..23 (each 32 elems = 64B)

  // combine decomposition: 256 threads, pairs of columns
  const int pb = tid >> 4;             // batch
  const int pj = (tid & 15) * 2;       // column pair
  const bool pact = (tid < BATCH * SLICE / 2);

  __syncthreads();

  for (int t = 0; t < TLEN + 3; t++) {
    // ---- dependency wait: all my flags >= t ----
    if (wave == 0) {
      const unsigned tgt = (unsigned)t;
      for (;;) {
        unsigned v = pollp ? agent_ld32(pollp) : 0xFFFFFFFFu;
        if (__ballot(v < tgt) == 0ull) break;
        __builtin_amdgcn_s_sleep(1);
      }
    }
    __syncthreads();

    const int par = t & 1;
    int tau;
    if      (grp == 0) tau = t;
    else if (grp == 1) tau = t - 1;
    else if (grp == 2) tau = t - 2;
    else               tau = t - 3;
    const bool active = (tau >= 0) && (tau < TLEN);
    const bool isL = (grp == 1 || grp == 3);

    if (active) {
      const int opar = tau & 1;

      // ---- early-issue combine-phase gx loads (produced in a prior tick) --
      unsigned long long gr01 = 0, gz01 = 0, gn01 = 0;
      const float* gxin = nullptr;
      if (isL) {
        gxin = ((grp == 1) ? gxbuf1 : gxbuf2) + ((size_t)(opar * WPG + wgi) * BATCH) * 96;
        if (pact) {
          const float* gxr = gxin + (size_t)pb * 96;
          gr01 = agent_ld64(gxr + pj);
          gz01 = agent_ld64(gxr + 32 + pj);
          gn01 = agent_ld64(gxr + 64 + pj);
        }
      }

      // ---- stage A tile (16 x 768) into LDS ----
      if (grp == 0) {
        // x[t] rows, plain cached loads (handles fp32 fallback too)
        const size_t srcbase = ((size_t)sb * TLEN + tau) * H + seg * 32;
        #pragma unroll
        for (int i = 0; i < 4; i++) {
          short8 v = loadA8(x, isbf, srcbase + i * 8);
          *(short8*)&h_lds[sb * HPAD + seg * 32 + i * 8] = v;
        }
      } else {
        const ushort* hsrc = ((grp == 3) ? h2buf : h1buf) + (size_t)par * (BATCH * H);
        const ushort* src = hsrc + (size_t)sb * H + seg * 32;
        U8 a, b;
        a.q[0] = agent_ld64(src +  0); a.q[1] = agent_ld64(src +  4);
        b.q[0] = agent_ld64(src +  8); b.q[1] = agent_ld64(src + 12);
        U8 c, d;
        c.q[0] = agent_ld64(src + 16); c.q[1] = agent_ld64(src + 20);
        d.q[0] = agent_ld64(src + 24); d.q[1] = agent_ld64(src + 28);
        ushort* dst = &h_lds[sb * HPAD + seg * 32];
        *(uint4*)(dst + 0)  = a.v4;
        *(uint4*)(dst + 8)  = b.v4;
        *(uint4*)(dst + 16) = c.v4;
        *(uint4*)(dst + 24) = d.v4;
      }
      __syncthreads();

      // ---- MFMA: A from LDS, B from registers ----
      const ushort* arow = &h_lds[(lane & 15) * HPAD + quad * 8];
      f32x4 acc0 = {0.f, 0.f, 0.f, 0.f}, acc1 = {0.f, 0.f, 0.f, 0.f};
      #pragma unroll
      for (int kk = 0; kk < 12; kk++) {
        short8 a0 = *(const short8*)(arow + kk * 32);
        short8 a1 = *(const short8*)(arow + (kk + 12) * 32);
        acc0 = __builtin_amdgcn_mfma_f32_16x16x32_bf16(a0, bfrag[kk],      acc0, 0, 0, 0);
        acc1 = __builtin_amdgcn_mfma_f32_16x16x32_bf16(a1, bfrag[kk + 12], acc1, 0, 0, 0);
      }
      f32x4 acc = acc0 + acc1;

      // ---- stage C tile to LDS ----
      #pragma unroll
      for (int i = 0; i < 4; i++)
        ghs[(gfbase + (lane & 15)) * 17 + quad * 4 + i] = acc[i];
      __syncthreads();

      if (!isL) {
        // pack gx slice [16][96] f32 -> 8B agent stores
        float* gxout = ((grp == 0) ? gxbuf1 : gxbuf2) + ((size_t)(par * WPG + wgi) * BATCH) * 96;
        const int m  = tid / 24;
        const int c4 = (tid % 24) * 4;
        union { unsigned long long q; float f[2]; } p0, p1;
        p0.f[0] = ghs[(c4 + 0) * 17 + m];
        p0.f[1] = ghs[(c4 + 1) * 17 + m];
        p1.f[0] = ghs[(c4 + 2) * 17 + m];
        p1.f[1] = ghs[(c4 + 3) * 17 + m];
        agent_st64(gxout + (size_t)m * 96 + c4,     p0.q);
        agent_st64(gxout + (size_t)m * 96 + c4 + 2, p1.q);
      } else if (pact) {
        union { unsigned long long q; float f[2]; } ur, uz, un;
        ur.q = gr01; uz.q = gz01; un.q = gn01;
        ushort* hout = ((grp == 1) ? h1buf : h2buf) + (size_t)opar * (BATCH * H);
        unsigned hpack = 0;
        #pragma unroll
        for (int s = 0; s < 2; s++) {
          const int j = pj + s;
          float rpre = ur.f[s] + bih_s[j]      + ghs[j * 17 + pb]        + bhh_s[j];
          float zpre = uz.f[s] + bih_s[32 + j] + ghs[(32 + j) * 17 + pb] + bhh_s[32 + j];
          float hn   = ghs[(64 + j) * 17 + pb] + bhh_s[64 + j];
          float r = 1.0f / (1.0f + expf(-rpre));
          float z = 1.0f / (1.0f + expf(-zpre));
          float n = tanhf(un.f[s] + bih_s[64 + j] + r * hn);
          float hnew = (1.0f - z) * n + z * hold[pb * SLICE + j];
          hold[pb * SLICE + j] = hnew;
          hpack |= ((unsigned)f2b(hnew)) << (16 * s);
        }
        agent_st32(&hout[(size_t)pb * H + wgi * SLICE + pj], hpack);
        if (grp == 3)
          *(unsigned*)&y2[((size_t)pb * TLEN + tau) * H + wgi * SLICE + pj] = hpack;
      }
    }

    // ---- post completion flag (after vmcnt drain) ----
    __syncthreads();                       // drains vmcnt: comms stores visible
    if (tid < 4) agent_st32(flagp(flags, grp, wgi, tid), (unsigned)(t + 1));
  }
}

// ---------------------------------------------------------------------------
// Final FC (768->512) + bias + exact GELU.  M=16384, N=512, K=768.
// ---------------------------------------------------------------------------
__global__ __launch_bounds__(256) void fc_kernel(
    const ushort* __restrict__ y2,     // [16384][768] bf16 (internal)
    const void* __restrict__ w_fc,     // [512][768]
    const void* __restrict__ b_fc,     // [512]
    const unsigned* __restrict__ dflag,
    void* __restrict__ out)            // [16384][512]
{
  const bool isbf = dflag[0] != 0u;
  const int wave = threadIdx.x >> 6;
  const int lane = threadIdx.x & 63;
  const int col  = lane & 15;
  const int quad = lane >> 4;
  const int m0 = blockIdx.x * 64 + wave * 16;
  const int n0 = blockIdx.y * 64;

  const ushort* arow = y2 + (size_t)(m0 + col) * H + quad * 8;
  const size_t bbase = (size_t)(n0 + col) * H + quad * 8;

  f32x4 acc[4];
  #pragma unroll
  for (int nt = 0; nt < 4; nt++) acc[nt] = (f32x4){0.f, 0.f, 0.f, 0.f};

  for (int kk = 0; kk < 24; kk++) {
    short8 a = *(const short8*)(arow + kk * 32);
    #pragma unroll
    for (int nt = 0; nt < 4; nt++) {
      short8 b = loadA8(w_fc, isbf, bbase + (size_t)nt * 16 * H + kk * 32);
      acc[nt] = __builtin_amdgcn_mfma_f32_16x16x32_bf16(a, b, acc[nt], 0, 0, 0);
    }
  }

  #pragma unroll
  for (int nt = 0; nt < 4; nt++) {
    #pragma unroll
    for (int i = 0; i < 4; i++) {
      int m = m0 + quad * 4 + i;
      int n = n0 + nt * 16 + col;
      float v = acc[nt][i] + loadS(b_fc, isbf, n);
      float g = 0.5f * v * (1.0f + erff(v * 0.70710678118654752f));
      if (isbf) ((ushort*)out)[(size_t)m * DOUT + n] = f2b(g);
      else      ((float*)out)[(size_t)m * DOUT + n] = g;
    }
  }
}

extern "C" void kernel_launch(void* const* d_in, const int* in_sizes, int n_in,
                              void* d_out, int out_size, void* d_ws, size_t ws_size,
                              hipStream_t stream) {
  const void* x    = d_in[0];
  const void* w_ih = d_in[1];
  const void* w_hh = d_in[2];
  const void* b_ih = d_in[3];
  const void* b_hh = d_in[4];
  const void* w_fc = d_in[5];
  const void* b_fc = d_in[6];

  char* ws = (char*)d_ws;
  // layout: [0,49152) flags[4][24][4] padded lines | [49152,49156) dflag |
  //         [53248,102400) h1 | [102400,151552) h2 |
  //         [151552,446464) gx1 | [446464,741376) gx2 | [741376,25907200) y2
  unsigned int* flags = (unsigned int*)(ws);
  unsigned int* dflag = (unsigned int*)(ws + 49152);
  ushort* h1buf  = (ushort*)(ws + 53248);
  ushort* h2buf  = (ushort*)(ws + 102400);
  float*  gxbuf1 = (float*)(ws + 151552);
  float*  gxbuf2 = (float*)(ws + 446464);
  ushort* y2     = (ushort*)(ws + 741376);

  hipMemsetAsync(ws, 0, 151552, stream);  // flags + dflag + h1 + h2
  scan_kernel<<<dim3(NWG), dim3(NTHR), 0, stream>>>(
      x, w_ih, w_hh, b_ih, b_hh, flags, dflag,
      h1buf, h2buf, gxbuf1, gxbuf2, y2);
  fc_kernel<<<dim3(16384 / 64, DOUT / 64), dim3(256), 0, stream>>>(
      y2, w_fc, b_fc, dflag, (void*)d_out);
}